// Round 1
// baseline (288.472 us; speedup 1.0000x reference)
//
#include <hip/hip_runtime.h>
#include <hip/hip_bf16.h>

typedef __bf16 bf16_t;
typedef bf16_t bf16x8 __attribute__((ext_vector_type(8)));
typedef bf16_t bf16x4 __attribute__((ext_vector_type(4)));
typedef float  f32x4  __attribute__((ext_vector_type(4)));

constexpr int B_ = 8, C_ = 512, HW_ = 4096, LC_ = 512, CTX_ = 768;

// ---------- prep kernels ----------

// in [rows][cols] f32 -> out [cols][rows] bf16
__global__ void k_transpose_w(const float* __restrict__ in, bf16_t* __restrict__ out,
                              int rows, int cols) {
    int idx = blockIdx.x * 256 + threadIdx.x;
    if (idx >= rows * cols) return;
    int r = idx % rows;
    int c = idx / rows;
    out[(size_t)c * rows + r] = (bf16_t)in[(size_t)r * cols + c];
}

// Wvo_t[c][j] = sum_m Wv[j][m] * Wo[m][c]   (c<512, j<768)
__global__ void k_wvo(const float* __restrict__ Wv, const float* __restrict__ Wo,
                      bf16_t* __restrict__ Wvo_t) {
    int idx = blockIdx.x * 256 + threadIdx.x;  // idx = j*512 + c
    int c = idx & 511;
    int j = idx >> 9;
    if (j >= CTX_) return;
    float s = 0.f;
    for (int m = 0; m < C_; ++m) s += Wv[(size_t)j * C_ + m] * Wo[(size_t)m * C_ + c];
    Wvo_t[(size_t)c * CTX_ + j] = (bf16_t)s;
}

// bvo[c] = bo[c] + sum_m bv[m]*Wo[m][c]
__global__ void k_bvo(const float* __restrict__ bv, const float* __restrict__ Wo,
                      const float* __restrict__ bo, float* __restrict__ bvo) {
    int c = blockIdx.x * 256 + threadIdx.x;
    if (c >= C_) return;
    float s = bo[c];
    for (int m = 0; m < C_; ++m) s += bv[m] * Wo[(size_t)m * C_ + c];
    bvo[c] = s;
}

__global__ void k_f32_to_bf16(const float* __restrict__ in, bf16_t* __restrict__ out, int n) {
    int i = (blockIdx.x * 256 + threadIdx.x) * 4;
    if (i >= n) return;
    f32x4 v = *(const f32x4*)(in + i);
    bf16x4 w;
    w[0] = (bf16_t)v.x; w[1] = (bf16_t)v.y; w[2] = (bf16_t)v.z; w[3] = (bf16_t)v.w;
    *(bf16x4*)(out + i) = w;
}

// x [B][C][HW] f32  ->  xt [B][HW][C] bf16
__global__ void k_transpose_x(const float* __restrict__ x, bf16_t* __restrict__ xt) {
    __shared__ float t[32][33];
    int b = blockIdx.z;
    int p0 = blockIdx.x * 32, c0 = blockIdx.y * 32;
    const float* xb = x + (size_t)b * C_ * HW_;
    bf16_t* xtb = xt + (size_t)b * HW_ * C_;
    int tx = threadIdx.x, ty = threadIdx.y;  // 32 x 8
#pragma unroll
    for (int i = 0; i < 4; ++i) {
        int c = c0 + ty + i * 8;
        t[ty + i * 8][tx] = xb[(size_t)c * HW_ + p0 + tx];
    }
    __syncthreads();
#pragma unroll
    for (int i = 0; i < 4; ++i) {
        int p = p0 + ty + i * 8;
        xtb[(size_t)p * C_ + c0 + tx] = (bf16_t)t[tx][ty + i * 8];
    }
}

// ---------- main GEMM ----------
// C[M][N] = A[M][K] @ B[K][N], A row-major bf16, Bt = B^T row-major [N][K] bf16.
// MODE 0: out bf16 [M][N], val = acc*scale + bias[n]
// MODE 1: out bf16 V^T layout: r -> (b=r>>9, l=r&511), store out[b][n][l] = acc + bias[n]
// MODE 2: out f32 [C][HW] per batch: out[n][r] = acc + xres[n][r]  (residual)
// M,N multiples of 128; K multiple of 32; all pointers 16B-aligned.
template <int MODE>
__global__ __launch_bounds__(256) void k_gemm(
    const bf16_t* __restrict__ A, int lda, long sA,
    const bf16_t* __restrict__ Bt, int ldb, long sB,
    const float* __restrict__ bias,
    void* __restrict__ out_, long sOut,
    const float* __restrict__ xres,
    int N, int K, float scale) {
    constexpr int LDR = 40;  // bf16 elems per LDS row (32 + 8 pad)
    __shared__ bf16_t lA[128 * LDR];
    __shared__ bf16_t lB[128 * LDR];
    const int z = blockIdx.z;
    A  += (size_t)z * sA;
    Bt += (size_t)z * sB;
    const int tid  = threadIdx.x;
    const int lane = tid & 63;
    const int wave = tid >> 6;
    const int wm = (wave >> 1) * 64, wn = (wave & 1) * 64;
    const int bm0 = blockIdx.y * 128, bn0 = blockIdx.x * 128;
    const int ar = lane & 15, kc = lane >> 4;

    f32x4 acc[4][4] = {};

    for (int k0 = 0; k0 < K; k0 += 32) {
        __syncthreads();
#pragma unroll
        for (int s = 0; s < 2; ++s) {
            int chunk = s * 256 + tid;      // 0..511 ; 16B chunks
            int row = chunk >> 2, c4 = chunk & 3;
            *(bf16x8*)&lA[row * LDR + c4 * 8] =
                *(const bf16x8*)&A[(size_t)(bm0 + row) * lda + k0 + c4 * 8];
            *(bf16x8*)&lB[row * LDR + c4 * 8] =
                *(const bf16x8*)&Bt[(size_t)(bn0 + row) * ldb + k0 + c4 * 8];
        }
        __syncthreads();
        bf16x8 af[4], bfr[4];
#pragma unroll
        for (int f = 0; f < 4; ++f) {
            af[f]  = *(const bf16x8*)&lA[(wm + f * 16 + ar) * LDR + kc * 8];
            bfr[f] = *(const bf16x8*)&lB[(wn + f * 16 + ar) * LDR + kc * 8];
        }
#pragma unroll
        for (int fm = 0; fm < 4; ++fm)
#pragma unroll
            for (int fn = 0; fn < 4; ++fn)
                acc[fm][fn] = __builtin_amdgcn_mfma_f32_16x16x32_bf16(
                    af[fm], bfr[fn], acc[fm][fn], 0, 0, 0);
    }

    const int rj = (lane >> 4) * 4;   // + j = row within 16x16 frag
    const int cj = lane & 15;         // col within frag

#pragma unroll
    for (int fm = 0; fm < 4; ++fm) {
#pragma unroll
        for (int fn = 0; fn < 4; ++fn) {
            int r0 = bm0 + wm + fm * 16 + rj;
            int cc = bn0 + wn + fn * 16 + cj;
            if constexpr (MODE == 0) {
                bf16_t* out = (bf16_t*)out_ + (size_t)z * sOut;
                float bb = bias ? bias[cc] : 0.f;
#pragma unroll
                for (int j = 0; j < 4; ++j)
                    out[(size_t)(r0 + j) * N + cc] = (bf16_t)(acc[fm][fn][j] * scale + bb);
            } else if constexpr (MODE == 1) {
                bf16_t* out = (bf16_t*)out_;
                int b = r0 >> 9, l0 = r0 & 511;
                float bb = bias[cc];
                bf16x4 v;
#pragma unroll
                for (int j = 0; j < 4; ++j) v[j] = (bf16_t)(acc[fm][fn][j] + bb);
                *(bf16x4*)&out[(size_t)b * C_ * LC_ + (size_t)cc * LC_ + l0] = v;
            } else {  // MODE 2
                float* out = (float*)out_ + (size_t)z * sOut;
                const float* xr = xres + (size_t)z * sOut;
                f32x4 xv = *(const f32x4*)&xr[(size_t)cc * HW_ + r0];
                f32x4 o;
#pragma unroll
                for (int j = 0; j < 4; ++j) o[j] = acc[fm][fn][j] + xv[j];
                *(f32x4*)&out[(size_t)cc * HW_ + r0] = o;
            }
        }
    }
}

// softmax over rows of 512, in place, bf16. 4 waves/block = 4 rows/block.
__global__ __launch_bounds__(256) void k_softmax(bf16_t* __restrict__ S) {
    int wave = threadIdx.x >> 6, lane = threadIdx.x & 63;
    size_t row = (size_t)blockIdx.x * 4 + wave;
    bf16_t* p = S + row * LC_;
    bf16x8 v = *(bf16x8*)&p[lane * 8];
    float f[8];
    float mx = -1e30f;
#pragma unroll
    for (int i = 0; i < 8; ++i) { f[i] = (float)v[i]; mx = fmaxf(mx, f[i]); }
#pragma unroll
    for (int o = 32; o > 0; o >>= 1) mx = fmaxf(mx, __shfl_xor(mx, o));
    float s = 0.f;
#pragma unroll
    for (int i = 0; i < 8; ++i) { f[i] = __expf(f[i] - mx); s += f[i]; }
#pragma unroll
    for (int o = 32; o > 0; o >>= 1) s += __shfl_xor(s, o);
    float inv = 1.f / s;
    bf16x8 w;
#pragma unroll
    for (int i = 0; i < 8; ++i) w[i] = (bf16_t)(f[i] * inv);
    *(bf16x8*)&p[lane * 8] = w;
}

extern "C" void kernel_launch(void* const* d_in, const int* in_sizes, int n_in,
                              void* d_out, int out_size, void* d_ws, size_t ws_size,
                              hipStream_t stream) {
    (void)in_sizes; (void)n_in; (void)out_size; (void)ws_size;
    const float* x   = (const float*)d_in[0];
    const float* ctx = (const float*)d_in[1];
    const float* Wq  = (const float*)d_in[2];
    const float* bq  = (const float*)d_in[3];
    const float* Wk  = (const float*)d_in[4];
    const float* bk  = (const float*)d_in[5];
    const float* Wv  = (const float*)d_in[6];
    const float* bv  = (const float*)d_in[7];
    const float* Wo  = (const float*)d_in[8];
    const float* bo  = (const float*)d_in[9];
    float* out = (float*)d_out;

    char* ws = (char*)d_ws;
    size_t off = 0;
    auto alloc = [&](size_t bytes) {
        char* p = ws + off;
        off += (bytes + 255) & ~(size_t)255;
        return p;
    };
    bf16_t* Wq_t  = (bf16_t*)alloc((size_t)C_ * C_ * 2);
    bf16_t* Wk_t  = (bf16_t*)alloc((size_t)C_ * CTX_ * 2);
    bf16_t* Wvo_t = (bf16_t*)alloc((size_t)C_ * CTX_ * 2);
    float*  bvo   = (float*)alloc((size_t)C_ * 4);
    bf16_t* ctxb  = (bf16_t*)alloc((size_t)B_ * LC_ * CTX_ * 2);
    bf16_t* xt    = (bf16_t*)alloc((size_t)B_ * HW_ * C_ * 2);
    bf16_t* Qb    = (bf16_t*)alloc((size_t)B_ * HW_ * C_ * 2);
    bf16_t* Kb    = (bf16_t*)alloc((size_t)B_ * LC_ * C_ * 2);
    bf16_t* Vt    = (bf16_t*)alloc((size_t)B_ * C_ * LC_ * 2);
    bf16_t* S     = (bf16_t*)alloc((size_t)B_ * HW_ * LC_ * 2);

    // weight prep
    k_transpose_w<<<(C_ * C_ + 255) / 256, 256, 0, stream>>>(Wq, Wq_t, C_, C_);
    k_transpose_w<<<(CTX_ * C_ + 255) / 256, 256, 0, stream>>>(Wk, Wk_t, CTX_, C_);
    k_wvo<<<(CTX_ * C_ + 255) / 256, 256, 0, stream>>>(Wv, Wo, Wvo_t);
    k_bvo<<<2, 256, 0, stream>>>(bv, Wo, bo, bvo);
    k_f32_to_bf16<<<(B_ * LC_ * CTX_ / 4 + 255) / 256, 256, 0, stream>>>(
        ctx, ctxb, B_ * LC_ * CTX_);
    k_transpose_x<<<dim3(HW_ / 32, C_ / 32, B_), dim3(32, 8), 0, stream>>>(x, xt);

    const float scale = 0.044194173824159216f;  // 512^-0.5

    // Q = xt @ Wq + bq        [32768][512]
    k_gemm<0><<<dim3(4, 256, 1), 256, 0, stream>>>(
        xt, C_, 0, Wq_t, C_, 0, bq, Qb, 0, nullptr, C_, C_, 1.f);
    // K = ctx @ Wk + bk       [4096][512]
    k_gemm<0><<<dim3(4, 32, 1), 256, 0, stream>>>(
        ctxb, CTX_, 0, Wk_t, CTX_, 0, bk, Kb, 0, nullptr, C_, CTX_, 1.f);
    // V' = ctx @ Wvo + bvo -> stored transposed [B][C][Lc]
    k_gemm<1><<<dim3(4, 32, 1), 256, 0, stream>>>(
        ctxb, CTX_, 0, Wvo_t, CTX_, 0, bvo, Vt, 0, nullptr, C_, CTX_, 1.f);
    // S = Q @ K^T * scale     per batch [4096][512]
    k_gemm<0><<<dim3(4, 32, 8), 256, 0, stream>>>(
        Qb, C_, (long)HW_ * C_, Kb, C_, (long)LC_ * C_, nullptr,
        S, (long)HW_ * LC_, nullptr, LC_, C_, scale);
    // softmax rows
    k_softmax<<<B_ * HW_ / 4, 256, 0, stream>>>(S);
    // out = x + (P @ V')^T    per batch, fp32
    k_gemm<2><<<dim3(4, 32, 8), 256, 0, stream>>>(
        S, LC_, (long)HW_ * LC_, Vt, LC_, (long)C_ * LC_, nullptr,
        out, (long)C_ * HW_, x, C_, LC_, 1.f);
}

// Round 2
// 252.030 us; speedup vs baseline: 1.1446x; 1.1446x over previous
//
#include <hip/hip_runtime.h>
#include <hip/hip_bf16.h>

typedef __bf16 bf16_t;
typedef bf16_t bf16x8 __attribute__((ext_vector_type(8)));
typedef bf16_t bf16x4 __attribute__((ext_vector_type(4)));
typedef float  f32x4  __attribute__((ext_vector_type(4)));

constexpr int B_ = 8, C_ = 512, HW_ = 4096, LC_ = 512, CTX_ = 768;

// ---------- prep kernels ----------

// tiled transpose+convert: in [R][Cc] f32 -> out [Cc][R] bf16. R,Cc multiples of 32.
__global__ void k_transpose_w(const float* __restrict__ in, bf16_t* __restrict__ out,
                              int R, int Cc) {
    __shared__ float t[32][33];
    int r0 = blockIdx.x * 32, c0 = blockIdx.y * 32;
    int tx = threadIdx.x, ty = threadIdx.y;  // 32 x 8
#pragma unroll
    for (int i = 0; i < 4; ++i)
        t[ty + i * 8][tx] = in[(size_t)(r0 + ty + i * 8) * Cc + c0 + tx];
    __syncthreads();
#pragma unroll
    for (int i = 0; i < 4; ++i)
        out[(size_t)(c0 + ty + i * 8) * R + r0 + tx] = (bf16_t)t[tx][ty + i * 8];
}

// bvo[c] = bo[c] + sum_m bv[m]*Wo[m][c]
__global__ void k_bvo(const float* __restrict__ bv, const float* __restrict__ Wo,
                      const float* __restrict__ bo, float* __restrict__ bvo) {
    int c = blockIdx.x * 256 + threadIdx.x;
    if (c >= C_) return;
    float s = bo[c];
    for (int m = 0; m < C_; ++m) s += bv[m] * Wo[(size_t)m * C_ + c];
    bvo[c] = s;
}

__global__ void k_f32_to_bf16(const float* __restrict__ in, bf16_t* __restrict__ out, int n) {
    int i = (blockIdx.x * 256 + threadIdx.x) * 4;
    if (i >= n) return;
    f32x4 v = *(const f32x4*)(in + i);
    bf16x4 w;
    w[0] = (bf16_t)v.x; w[1] = (bf16_t)v.y; w[2] = (bf16_t)v.z; w[3] = (bf16_t)v.w;
    *(bf16x4*)(out + i) = w;
}

// x [B][C][HW] f32  ->  xt [B][HW][C] bf16
__global__ void k_transpose_x(const float* __restrict__ x, bf16_t* __restrict__ xt) {
    __shared__ float t[32][33];
    int b = blockIdx.z;
    int p0 = blockIdx.x * 32, c0 = blockIdx.y * 32;
    const float* xb = x + (size_t)b * C_ * HW_;
    bf16_t* xtb = xt + (size_t)b * HW_ * C_;
    int tx = threadIdx.x, ty = threadIdx.y;  // 32 x 8
#pragma unroll
    for (int i = 0; i < 4; ++i) {
        int c = c0 + ty + i * 8;
        t[ty + i * 8][tx] = xb[(size_t)c * HW_ + p0 + tx];
    }
    __syncthreads();
#pragma unroll
    for (int i = 0; i < 4; ++i) {
        int p = p0 + ty + i * 8;
        xtb[(size_t)p * C_ + c0 + tx] = (bf16_t)t[tx][ty + i * 8];
    }
}

// ---------- main GEMM ----------
// C[M][N] = A[M][K] @ B[K][N], A row-major bf16, Bt = B^T row-major [N][K] bf16.
// MODE 0: out bf16 [M][N], val = acc*scale + bias[n]
// MODE 1: out bf16 V^T layout: r -> (b=r>>9, l=r&511), store out[b][n][l] = acc + bias[n]
// MODE 2: out f32 [C][HW] per batch: out[n][r] = acc + xres[n][r]  (residual)
// MODE 3: out bf16 transposed [N][Mtot], Mtot passed in sOut: out[n][m] = acc
// M,N multiples of 128; K multiple of 32; all pointers 16B-aligned.
template <int MODE>
__global__ __launch_bounds__(256) void k_gemm(
    const bf16_t* __restrict__ A, int lda, long sA,
    const bf16_t* __restrict__ Bt, int ldb, long sB,
    const float* __restrict__ bias,
    void* __restrict__ out_, long sOut,
    const float* __restrict__ xres,
    int N, int K, float scale) {
    __shared__ bf16_t lA[128 * 32];   // linear, unpadded (global_load_lds dest)
    __shared__ bf16_t lB[128 * 32];
    const int z = blockIdx.z;
    A  += (size_t)z * sA;
    Bt += (size_t)z * sB;
    const int tid  = threadIdx.x;
    const int lane = tid & 63;
    const int wave = tid >> 6;
    const int wm = (wave >> 1) * 64, wn = (wave & 1) * 64;
    const int bm0 = blockIdx.y * 128, bn0 = blockIdx.x * 128;
    const int ar = lane & 15, kc = lane >> 4;

    auto lA3 = (__attribute__((address_space(3))) char*)&lA[0];
    auto lB3 = (__attribute__((address_space(3))) char*)&lB[0];

    f32x4 acc[4][4] = {};

    for (int k0 = 0; k0 < K; k0 += 32) {
        __syncthreads();  // previous tile's reads done before overwrite
#pragma unroll
        for (int s = 0; s < 2; ++s) {
            // each wave stages two 1024B chunks of A and of B, direct to LDS
            int wchunk = wave * 2 + s;            // 0..7 (wave-uniform)
            int id = wchunk * 64 + lane;          // 0..511 ; 16B units
            int row = id >> 2, c4 = id & 3;       // 4 x 16B per 64B LDS row
            __builtin_amdgcn_global_load_lds(
                (const __attribute__((address_space(1))) void*)
                    &A[(size_t)(bm0 + row) * lda + k0 + c4 * 8],
                (__attribute__((address_space(3))) void*)(lA3 + wchunk * 1024),
                16, 0, 0);
            __builtin_amdgcn_global_load_lds(
                (const __attribute__((address_space(1))) void*)
                    &Bt[(size_t)(bn0 + row) * ldb + k0 + c4 * 8],
                (__attribute__((address_space(3))) void*)(lB3 + wchunk * 1024),
                16, 0, 0);
        }
        __syncthreads();  // compiler drains vmcnt before barrier
        bf16x8 af[4], bfr[4];
#pragma unroll
        for (int f = 0; f < 4; ++f) {
            af[f]  = *(const bf16x8*)&lA[(wm + f * 16 + ar) * 32 + kc * 8];
            bfr[f] = *(const bf16x8*)&lB[(wn + f * 16 + ar) * 32 + kc * 8];
        }
#pragma unroll
        for (int fm = 0; fm < 4; ++fm)
#pragma unroll
            for (int fn = 0; fn < 4; ++fn)
                acc[fm][fn] = __builtin_amdgcn_mfma_f32_16x16x32_bf16(
                    af[fm], bfr[fn], acc[fm][fn], 0, 0, 0);
    }

    const int rj = (lane >> 4) * 4;   // + j = row within 16x16 frag
    const int cj = lane & 15;         // col within frag

#pragma unroll
    for (int fm = 0; fm < 4; ++fm) {
#pragma unroll
        for (int fn = 0; fn < 4; ++fn) {
            int r0 = bm0 + wm + fm * 16 + rj;
            int cc = bn0 + wn + fn * 16 + cj;
            if constexpr (MODE == 0) {
                bf16_t* out = (bf16_t*)out_ + (size_t)z * sOut;
                float bb = bias ? bias[cc] : 0.f;
#pragma unroll
                for (int j = 0; j < 4; ++j)
                    out[(size_t)(r0 + j) * N + cc] = (bf16_t)(acc[fm][fn][j] * scale + bb);
            } else if constexpr (MODE == 1) {
                bf16_t* out = (bf16_t*)out_;
                int b = r0 >> 9, l0 = r0 & 511;
                float bb = bias[cc];
                bf16x4 v;
#pragma unroll
                for (int j = 0; j < 4; ++j) v[j] = (bf16_t)(acc[fm][fn][j] + bb);
                *(bf16x4*)&out[(size_t)b * C_ * LC_ + (size_t)cc * LC_ + l0] = v;
            } else if constexpr (MODE == 2) {
                float* out = (float*)out_ + (size_t)z * sOut;
                const float* xr = xres + (size_t)z * sOut;
                f32x4 xv = *(const f32x4*)&xr[(size_t)cc * HW_ + r0];
                f32x4 o;
#pragma unroll
                for (int j = 0; j < 4; ++j) o[j] = acc[fm][fn][j] + xv[j];
                *(f32x4*)&out[(size_t)cc * HW_ + r0] = o;
            } else {  // MODE 3: transposed bf16, ld = sOut (total M rows)
                bf16_t* out = (bf16_t*)out_;
                bf16x4 v;
#pragma unroll
                for (int j = 0; j < 4; ++j) v[j] = (bf16_t)acc[fm][fn][j];
                *(bf16x4*)&out[(size_t)cc * sOut + r0] = v;
            }
        }
    }
}

// softmax over rows of 512, in place, bf16. 4 waves/block = 4 rows/block.
__global__ __launch_bounds__(256) void k_softmax(bf16_t* __restrict__ S) {
    int wave = threadIdx.x >> 6, lane = threadIdx.x & 63;
    size_t row = (size_t)blockIdx.x * 4 + wave;
    bf16_t* p = S + row * LC_;
    bf16x8 v = *(bf16x8*)&p[lane * 8];
    float f[8];
    float mx = -1e30f;
#pragma unroll
    for (int i = 0; i < 8; ++i) { f[i] = (float)v[i]; mx = fmaxf(mx, f[i]); }
#pragma unroll
    for (int o = 32; o > 0; o >>= 1) mx = fmaxf(mx, __shfl_xor(mx, o));
    float s = 0.f;
#pragma unroll
    for (int i = 0; i < 8; ++i) { f[i] = __expf(f[i] - mx); s += f[i]; }
#pragma unroll
    for (int o = 32; o > 0; o >>= 1) s += __shfl_xor(s, o);
    float inv = 1.f / s;
    bf16x8 w;
#pragma unroll
    for (int i = 0; i < 8; ++i) w[i] = (bf16_t)(f[i] * inv);
    *(bf16x8*)&p[lane * 8] = w;
}

extern "C" void kernel_launch(void* const* d_in, const int* in_sizes, int n_in,
                              void* d_out, int out_size, void* d_ws, size_t ws_size,
                              hipStream_t stream) {
    (void)in_sizes; (void)n_in; (void)out_size; (void)ws_size;
    const float* x   = (const float*)d_in[0];
    const float* ctx = (const float*)d_in[1];
    const float* Wq  = (const float*)d_in[2];
    const float* bq  = (const float*)d_in[3];
    const float* Wk  = (const float*)d_in[4];
    const float* bk  = (const float*)d_in[5];
    const float* Wv  = (const float*)d_in[6];
    const float* bv  = (const float*)d_in[7];
    const float* Wo  = (const float*)d_in[8];
    const float* bo  = (const float*)d_in[9];
    float* out = (float*)d_out;

    char* ws = (char*)d_ws;
    size_t off = 0;
    auto alloc = [&](size_t bytes) {
        char* p = ws + off;
        off += (bytes + 255) & ~(size_t)255;
        return p;
    };
    bf16_t* Wq_t  = (bf16_t*)alloc((size_t)C_ * C_ * 2);
    bf16_t* Wk_t  = (bf16_t*)alloc((size_t)C_ * CTX_ * 2);
    bf16_t* Wvo_t = (bf16_t*)alloc((size_t)C_ * CTX_ * 2);
    bf16_t* Wv_b  = (bf16_t*)alloc((size_t)CTX_ * C_ * 2);
    bf16_t* Wo_t  = (bf16_t*)alloc((size_t)C_ * C_ * 2);
    float*  bvo   = (float*)alloc((size_t)C_ * 4);
    bf16_t* ctxb  = (bf16_t*)alloc((size_t)B_ * LC_ * CTX_ * 2);
    bf16_t* xt    = (bf16_t*)alloc((size_t)B_ * HW_ * C_ * 2);
    bf16_t* Qb    = (bf16_t*)alloc((size_t)B_ * HW_ * C_ * 2);
    bf16_t* Kb    = (bf16_t*)alloc((size_t)B_ * LC_ * C_ * 2);
    bf16_t* Vt    = (bf16_t*)alloc((size_t)B_ * C_ * LC_ * 2);
    bf16_t* S     = (bf16_t*)alloc((size_t)B_ * HW_ * LC_ * 2);

    // weight prep (all tiled/coalesced)
    k_transpose_w<<<dim3(C_ / 32, C_ / 32), dim3(32, 8), 0, stream>>>(Wq, Wq_t, C_, C_);
    k_transpose_w<<<dim3(CTX_ / 32, C_ / 32), dim3(32, 8), 0, stream>>>(Wk, Wk_t, CTX_, C_);
    k_transpose_w<<<dim3(C_ / 32, C_ / 32), dim3(32, 8), 0, stream>>>(Wo, Wo_t, C_, C_);
    k_f32_to_bf16<<<(CTX_ * C_ / 4 + 255) / 256, 256, 0, stream>>>(Wv, Wv_b, CTX_ * C_);
    k_bvo<<<2, 256, 0, stream>>>(bv, Wo, bo, bvo);
    k_f32_to_bf16<<<(B_ * LC_ * CTX_ / 4 + 255) / 256, 256, 0, stream>>>(
        ctx, ctxb, B_ * LC_ * CTX_);
    k_transpose_x<<<dim3(HW_ / 32, C_ / 32, B_), dim3(32, 8), 0, stream>>>(x, xt);

    const float scale = 0.044194173824159216f;  // 512^-0.5

    // Wvo_t[c][j] = (Wv @ Wo)^T : M=768, N=512, K=512, MODE 3 transposed store
    k_gemm<3><<<dim3(4, 6, 1), 256, 0, stream>>>(
        Wv_b, C_, 0, Wo_t, C_, 0, nullptr, Wvo_t, CTX_, nullptr, C_, C_, 1.f);
    // Q = xt @ Wq + bq        [32768][512]
    k_gemm<0><<<dim3(4, 256, 1), 256, 0, stream>>>(
        xt, C_, 0, Wq_t, C_, 0, bq, Qb, 0, nullptr, C_, C_, 1.f);
    // K = ctx @ Wk + bk       [4096][512]
    k_gemm<0><<<dim3(4, 32, 1), 256, 0, stream>>>(
        ctxb, CTX_, 0, Wk_t, CTX_, 0, bk, Kb, 0, nullptr, C_, CTX_, 1.f);
    // V' = ctx @ Wvo + bvo -> stored transposed [B][C][Lc]
    k_gemm<1><<<dim3(4, 32, 1), 256, 0, stream>>>(
        ctxb, CTX_, 0, Wvo_t, CTX_, 0, bvo, Vt, 0, nullptr, C_, CTX_, 1.f);
    // S = Q @ K^T * scale     per batch [4096][512]
    k_gemm<0><<<dim3(4, 32, 8), 256, 0, stream>>>(
        Qb, C_, (long)HW_ * C_, Kb, C_, (long)LC_ * C_, nullptr,
        S, (long)HW_ * LC_, nullptr, LC_, C_, scale);
    // softmax rows
    k_softmax<<<B_ * HW_ / 4, 256, 0, stream>>>(S);
    // out = x + (P @ V')^T    per batch, fp32
    k_gemm<2><<<dim3(4, 32, 8), 256, 0, stream>>>(
        S, LC_, (long)HW_ * LC_, Vt, LC_, (long)C_ * LC_, nullptr,
        out, (long)C_ * HW_, x, C_, LC_, 1.f);
}